// Round 16
// baseline (416.973 us; speedup 1.0000x reference)
//
#include <hip/hip_runtime.h>
#include <hip/hip_bf16.h>
#include <stdint.h>

#define DIN 4096
#define DOUT 4096
#define NK 128   // 32-wide k-steps

typedef __attribute__((ext_vector_type(8))) short short8;
typedef __attribute__((ext_vector_type(8))) unsigned short ushort8;
typedef __attribute__((ext_vector_type(16))) float f32x16;

__device__ inline unsigned short f2bf(float f) {
    union { float f; unsigned u; } v; v.f = f;
    unsigned r = v.u + 0x7fffu + ((v.u >> 16) & 1u);   // RNE
    return (unsigned short)(r >> 16);
}

// ============ blocked workspace layout (h-major, r13-verified) ==============
// elem offset for (R=row/256, slice v=0..127, mt=row%256/32, s=kslice, h, r32):
//   R*1048576 + v*8192 + mt*1024 + s*512 + h*256 + r32*8
// Every (mt,s) fragment of a slice is a contiguous lane-ordered 1KB block ->
// BOTH operands load directly global->VGPR as one dwordx4 per lane (r16).

// ---- prep 1: x (f32) -> blocked bf16 (r13-verified) -------------------------
__global__ void cvt_x_blocked(const float* __restrict__ x, ushort* __restrict__ xb) {
    const int t = threadIdx.x;                 // 256
    const int bx = blockIdx.x;                 // (M/256)*64
    const int R = bx >> 6, u = bx & 63;
    const int r32 = t >> 3, kcol = t & 7;
    const int kk = kcol >> 2, s = (kcol >> 1) & 1, h = kcol & 1;
    const float* src = x + ((size_t)R * 256) * DIN + u * 64 + kcol * 8;
    ushort* dst = xb + (size_t)R * 1048576 + (size_t)u * 16384
                + (size_t)kk * 8192 + s * 512 + h * 256 + r32 * 8;
#pragma unroll
    for (int j = 0; j < 8; ++j) {
        const float* p = src + ((size_t)(j * 32 + r32)) * DIN;
        float4 v0 = *(const float4*)p, v1 = *(const float4*)(p + 4);
        ushort8 o;
        o[0] = f2bf(v0.x); o[1] = f2bf(v0.y); o[2] = f2bf(v0.z); o[3] = f2bf(v0.w);
        o[4] = f2bf(v1.x); o[5] = f2bf(v1.y); o[6] = f2bf(v1.z); o[7] = f2bf(v1.w);
        *(ushort8*)(dst + (size_t)j * 1024) = o;
    }
}

// ---- prep 2a: Wt[e][d] = bf16(base[d][e] + c*mask[d][e]) (verified) ---------
__global__ void make_wt_kernel(const float* __restrict__ base, const int* __restrict__ mask,
                               const float* __restrict__ coeff, ushort* __restrict__ wt) {
    __shared__ float tile[64][65];
    const float c = coeff[0];
    const int t = threadIdx.x;
    const int bd = blockIdx.x >> 6;
    const int be = blockIdx.x & 63;
    const int d0 = bd * 64, e0 = be * 64;
#pragma unroll
    for (int i = 0; i < 4; ++i) {
        int idx = i * 256 + t;
        int r = idx >> 4;
        int c4 = (idx & 15) << 2;
        const float4 bv = *(const float4*)(base + (size_t)(d0 + r) * DOUT + e0 + c4);
        const int4  mv = *(const int4*)(mask + (size_t)(d0 + r) * DOUT + e0 + c4);
        tile[r][c4 + 0] = bv.x + c * (float)mv.x;
        tile[r][c4 + 1] = bv.y + c * (float)mv.y;
        tile[r][c4 + 2] = bv.z + c * (float)mv.z;
        tile[r][c4 + 3] = bv.w + c * (float)mv.w;
    }
    __syncthreads();
#pragma unroll
    for (int i = 0; i < 8; ++i) {
        int idx = i * 256 + t;
        int r = idx >> 5;
        int p = (idx & 31) << 1;
        ushort2 o;
        o.x = f2bf(tile[p][r]);
        o.y = f2bf(tile[p + 1][r]);
        *(ushort2*)(wt + (size_t)(e0 + r) * DIN + d0 + p) = o;
    }
}

// ---- prep 2b: row-major Wt -> blocked (h-major, r13-verified) ---------------
__global__ void reblock_w(const ushort* __restrict__ wt_rm, ushort* __restrict__ wb) {
    const int t = threadIdx.x;
    const int bx = blockIdx.x;
    const int R = bx >> 6, u = bx & 63;
    const int r32 = t >> 3, kcol = t & 7;
    const int kk = kcol >> 2, s = (kcol >> 1) & 1, h = kcol & 1;
    const ushort* src = wt_rm + ((size_t)R * 256) * DIN + u * 64 + kcol * 8;
    ushort* dst = wb + (size_t)R * 1048576 + (size_t)u * 16384
                + (size_t)kk * 8192 + s * 512 + h * 256 + r32 * 8;
#pragma unroll
    for (int j = 0; j < 8; ++j) {
        ushort8 o = *(const ushort8*)(src + ((size_t)(j * 32 + r32)) * DIN);
        *(ushort8*)(dst + (size_t)j * 1024) = o;
    }
}

// ---- GEMM: 256x256, ZERO LDS / ZERO barriers: all operands global->reg ------
// Round-16: r15's diagnosis said LDS-port time (~2300 cyc/K-tile/CU) is
// serialized with MFMA (~2064) by the barrier structure; r15 removed half and
// kept the sync chain (regressed). This removes everything: no LDS, no
// barriers, no manual waitcnt. Manual 1-step E/O register double-buffer;
// compiler inserts counted vmcnt before first use; waves free-run (m114
// overlap). Redundant same-address frag reads (2x A, 4x B per CU) are
// expected L1/L2 hits.

#define MFMA32(D, VA, VB) D = __builtin_amdgcn_mfma_f32_32x32x16_bf16(VA, VB, D, 0, 0, 0)

#define PRIO1 __builtin_amdgcn_s_setprio(1);
#define PRIO0 __builtin_amdgcn_s_setprio(0);

// A frags (mt,s): mt*1024 + s*512 ; index = mt*2+s
#define LDA(X, OFF) { \
    X##0 = *(const short8*)(aP + (OFF));        X##1 = *(const short8*)(aP + (OFF) + 512); \
    X##2 = *(const short8*)(aP + (OFF) + 1024); X##3 = *(const short8*)(aP + (OFF) + 1536); }
// B frags (nt,s): nt*1024 + s*512 ; index = nt*2+s
#define LDB(X, OFF) { \
    X##0 = *(const short8*)(bP + (OFF));        X##1 = *(const short8*)(bP + (OFF) + 512); \
    X##2 = *(const short8*)(bP + (OFF) + 1024); X##3 = *(const short8*)(bP + (OFF) + 1536); \
    X##4 = *(const short8*)(bP + (OFF) + 2048); X##5 = *(const short8*)(bP + (OFF) + 2560); \
    X##6 = *(const short8*)(bP + (OFF) + 3072); X##7 = *(const short8*)(bP + (OFF) + 3584); }

// 16 MFMA: c[mt][nt] += a(mt,s0)*b(nt,s0) + a(mt,s1)*b(nt,s1)
#define MFMA16(AX, BX) \
    MFMA32(c00, AX##0, BX##0); MFMA32(c00, AX##1, BX##1); \
    MFMA32(c01, AX##0, BX##2); MFMA32(c01, AX##1, BX##3); \
    MFMA32(c02, AX##0, BX##4); MFMA32(c02, AX##1, BX##5); \
    MFMA32(c03, AX##0, BX##6); MFMA32(c03, AX##1, BX##7); \
    MFMA32(c10, AX##2, BX##0); MFMA32(c10, AX##3, BX##1); \
    MFMA32(c11, AX##2, BX##2); MFMA32(c11, AX##3, BX##3); \
    MFMA32(c12, AX##2, BX##4); MFMA32(c12, AX##3, BX##5); \
    MFMA32(c13, AX##2, BX##6); MFMA32(c13, AX##3, BX##7);

__global__ __launch_bounds__(512, 2) void gemm_kernel(const ushort* __restrict__ A,
                                                      const ushort* __restrict__ Bt,
                                                      float* __restrict__ C) {
    const int tid = threadIdx.x;
    const int lane = tid & 63;
    const int wave = tid >> 6;

    const int nbn = DOUT / 256;               // 16
    const int nwg = gridDim.x;                // 512
    int bid = blockIdx.x;
    int cpx = nwg >> 3;
    int s = (bid & 7) * cpx + (bid >> 3);     // XCD-contiguous chunks
    const int m0 = (s / nbn) * 256;
    const int n0 = (s % nbn) * 256;

    const int wr = wave >> 1;                 // 0..3  (M quarter: 2 mt of 32)
    const int wc = wave & 1;                  // 0..1  (N half: 4 nt of 32)
    const int fr = lane & 31;
    const int fq = lane >> 5;

    // per-wave fragment base pointers (lane-ordered contiguous 1KB frags)
    const ushort* aP = A  + (size_t)(m0 >> 8) * 1048576
                     + (wr * 2) * 1024 + fq * 256 + fr * 8;
    const ushort* bP = Bt + (size_t)(n0 >> 8) * 1048576
                     + (wc * 4) * 1024 + fq * 256 + fr * 8;

    f32x16 c00 = {}, c01 = {}, c02 = {}, c03 = {};
    f32x16 c10 = {}, c11 = {}, c12 = {}, c13 = {};
    short8 aE0, aE1, aE2, aE3, aO0, aO1, aO2, aO3;
    short8 bE0, bE1, bE2, bE3, bE4, bE5, bE6, bE7;
    short8 bO0, bO1, bO2, bO3, bO4, bO5, bO6, bO7;

    // prologue: slice 0 -> E regs
    LDA(aE, 0) LDB(bE, 0)

    // steady: load O(v+1) under MFMA(E=v); load E(v+2) under MFMA(O=v+1)
    for (int v = 0; v < NK - 2; v += 2) {
        LDA(aO, 8192)  LDB(bO, 8192)
        PRIO1 MFMA16(aE, bE) PRIO0
        LDA(aE, 16384) LDB(bE, 16384)
        PRIO1 MFMA16(aO, bO) PRIO0
        aP += 16384; bP += 16384;
    }
    // tail: slices 126 (E, loaded last iter), 127 (O)
    LDA(aO, 8192) LDB(bO, 8192)
    PRIO1 MFMA16(aE, bE) PRIO0
    PRIO1 MFMA16(aO, bO) PRIO0

    // epilogue (r15-verified 4x2 mapping; 32x32 C/D: col=fr, row=(r&3)+8*(r>>2)+4*fq)
    const int gcb = n0 + wc * 128 + fr;
    const int grb = m0 + wr * 64 + fq * 4;
#define WRT(CT, MT, NN) \
    _Pragma("unroll") \
    for (int r = 0; r < 16; ++r) { \
        int grow = grb + (MT) * 32 + (r & 3) + 8 * (r >> 2); \
        C[(size_t)grow * DOUT + gcb + (NN) * 32] = CT[r]; \
    }
    WRT(c00, 0, 0) WRT(c01, 0, 1) WRT(c02, 0, 2) WRT(c03, 0, 3)
    WRT(c10, 1, 0) WRT(c11, 1, 1) WRT(c12, 1, 2) WRT(c13, 1, 3)
#undef WRT
}

extern "C" void kernel_launch(void* const* d_in, const int* in_sizes, int n_in,
                              void* d_out, int out_size, void* d_ws, size_t ws_size,
                              hipStream_t stream) {
    const float* x = (const float*)d_in[0];
    const float* base = (const float*)d_in[1];
    const float* coeff = (const float*)d_in[2];
    const int* mask = (const int*)d_in[3];
    float* out = (float*)d_out;

    const int M = in_sizes[0] / DIN;           // 8192
    ushort* xb = (ushort*)d_ws;                // M*DIN bf16 blocked (64 MB)
    ushort* wb = xb + (size_t)M * DIN;         // DOUT*DIN bf16 blocked (32 MB)
    ushort* wt_rm = (ushort*)d_out;            // scratch: row-major Wt (32 MB),
                                               // fully overwritten by gemm later

    cvt_x_blocked<<<(M / 256) * 64, 256, 0, stream>>>(x, xb);
    make_wt_kernel<<<(DIN / 64) * (DOUT / 64), 256, 0, stream>>>(base, mask, coeff, wt_rm);
    reblock_w<<<(DOUT / 256) * 64, 256, 0, stream>>>(wt_rm, wb);

    const int nwg = (M / 256) * (DOUT / 256);  // 512
    gemm_kernel<<<nwg, 512, 0, stream>>>(xb, wb, out);
}

// Round 17
// 313.619 us; speedup vs baseline: 1.3296x; 1.3296x over previous
//
#include <hip/hip_runtime.h>
#include <hip/hip_bf16.h>
#include <stdint.h>

#define DIN 4096
#define DOUT 4096
#define BK 64
#define NT (DIN / BK)   // 64 K-tiles

typedef __attribute__((ext_vector_type(8))) short short8;
typedef __attribute__((ext_vector_type(8))) unsigned short ushort8;
typedef __attribute__((ext_vector_type(4))) float f32x4;

__device__ inline unsigned short f2bf(float f) {
    union { float f; unsigned u; } v; v.f = f;
    unsigned r = v.u + 0x7fffu + ((v.u >> 16) & 1u);   // RNE
    return (unsigned short)(r >> 16);
}

// ---- prep 1: x (f32) -> bf16, 8 elems/thread --------------------------------
__global__ void cvt_x_kernel(const float* __restrict__ x, ushort* __restrict__ xb, long n8) {
    long i = (long)blockIdx.x * blockDim.x + threadIdx.x;
    if (i >= n8) return;
    const float4* p = (const float4*)(x + i * 8);
    float4 v0 = p[0], v1 = p[1];
    ushort8 o;
    o[0] = f2bf(v0.x); o[1] = f2bf(v0.y); o[2] = f2bf(v0.z); o[3] = f2bf(v0.w);
    o[4] = f2bf(v1.x); o[5] = f2bf(v1.y); o[6] = f2bf(v1.z); o[7] = f2bf(v1.w);
    *(ushort8*)(xb + i * 8) = o;
}

// ---- prep 2: Wt[e][d] = bf16(base[d][e] + c*mask[d][e])  (64x64 LDS transpose)
__global__ void make_wt_kernel(const float* __restrict__ base, const int* __restrict__ mask,
                               const float* __restrict__ coeff, ushort* __restrict__ wt) {
    __shared__ float tile[64][65];
    const float c = coeff[0];
    const int t = threadIdx.x;                 // 256 threads
    const int bd = blockIdx.x >> 6;            // d-tile
    const int be = blockIdx.x & 63;            // e-tile
    const int d0 = bd * 64, e0 = be * 64;
#pragma unroll
    for (int i = 0; i < 4; ++i) {
        int idx = i * 256 + t;                 // 0..1023 float4-index
        int r = idx >> 4;                      // d-row 0..63
        int c4 = (idx & 15) << 2;              // e-col
        const float4 bv = *(const float4*)(base + (size_t)(d0 + r) * DOUT + e0 + c4);
        const int4  mv = *(const int4*)(mask + (size_t)(d0 + r) * DOUT + e0 + c4);
        tile[r][c4 + 0] = bv.x + c * (float)mv.x;
        tile[r][c4 + 1] = bv.y + c * (float)mv.y;
        tile[r][c4 + 2] = bv.z + c * (float)mv.z;
        tile[r][c4 + 3] = bv.w + c * (float)mv.w;
    }
    __syncthreads();
#pragma unroll
    for (int i = 0; i < 8; ++i) {
        int idx = i * 256 + t;                 // 0..2047 pair index
        int r = idx >> 5;                      // e-row 0..63
        int p = (idx & 31) << 1;               // d-col pair
        ushort2 o;
        o.x = f2bf(tile[p][r]);
        o.y = f2bf(tile[p + 1][r]);
        *(ushort2*)(wt + (size_t)(e0 + r) * DIN + d0 + p) = o;
    }
}

// ---- GEMM: 256x256 tile, BK=64, 8-phase, de-lockstepped (r9, best: 270us) ---
// Post-MFMA barriers removed (5 barriers per K-tile). Every STAGE issue is
// protected by a PRE-MFMA barrier that transitively guarantees all prior
// reads of its target region completed. vmcnt: mid-tile WAITV(6) before ph2
// reads, boundary WAITV(6)/WAITV(0); all waits target loads >=3 phases old.
// Waves de-phase by one region: a wave finishing MFMA (setprio 0) issues next
// reads/stages while the other wave on its SIMD is still MFMA-ing (setprio 1).

#define MFMA(d, va, vb) d = __builtin_amdgcn_mfma_f32_16x16x32_bf16(va, vb, d, 0, 0, 0)

#define GLL(P, L) \
    __builtin_amdgcn_global_load_lds( \
        (const __attribute__((address_space(1))) void*)(P), \
        (__attribute__((address_space(3))) void*)(L), 16, 0, 0)

#define RDA(BUF,KK,OH,MM) (*(const short8*)&lA[BUF][KK][aoff + (OH)*2048 + (MM)*512])
#define RDB(BUF,KK,NN)    (*(const short8*)&lB[BUF][KK][boff + (NN)*512])

#define STAGE_A(BUF,KK,OFE) { GLL(gA0 + (OFE), &lA[BUF][KK][doff]); \
                              GLL(gA1 + (OFE), &lA[BUF][KK][doff + 4096]); }
#define STAGE_B(BUF,KK,OFE) { GLL(gB0 + (OFE), &lB[BUF][KK][doff]); \
                              GLL(gB1 + (OFE), &lB[BUF][KK][doff + 4096]); }

#define WAITV(N)  asm volatile("s_waitcnt vmcnt(" #N ")" ::: "memory")

#define PHASE_CORE(AOFF) \
    __builtin_amdgcn_s_barrier(); \
    __builtin_amdgcn_s_setprio(1); \
    MFMA(acc[AOFF+0][0],a0,b0); MFMA(acc[AOFF+0][1],a0,b1); MFMA(acc[AOFF+0][2],a0,b2); MFMA(acc[AOFF+0][3],a0,b3); \
    MFMA(acc[AOFF+1][0],a1,b0); MFMA(acc[AOFF+1][1],a1,b1); MFMA(acc[AOFF+1][2],a1,b2); MFMA(acc[AOFF+1][3],a1,b3); \
    MFMA(acc[AOFF+2][0],a2,b0); MFMA(acc[AOFF+2][1],a2,b1); MFMA(acc[AOFF+2][2],a2,b2); MFMA(acc[AOFF+2][3],a2,b3); \
    MFMA(acc[AOFF+3][0],a3,b0); MFMA(acc[AOFF+3][1],a3,b1); MFMA(acc[AOFF+3][2],a3,b2); MFMA(acc[AOFF+3][3],a3,b3); \
    __builtin_amdgcn_s_setprio(0);

// K-tile: 4 phases; stage schedule:
//  ph1: stage A.kk1(U+1)->other buf   ph2: stage B.kk1(U+1)
//  ph3: stage A.kk0(U+2)->this buf    ph4: stage B.kk0(U+2)
#define KTILE(BUF, G1, G2, NEXT, OFE1, OFE2) \
  { \
    short8 a0,a1,a2,a3,b0,b1,b2,b3; \
    a0=RDA(BUF,0,0,0); a1=RDA(BUF,0,0,1); a2=RDA(BUF,0,0,2); a3=RDA(BUF,0,0,3); \
    b0=RDB(BUF,0,0); b1=RDB(BUF,0,1); b2=RDB(BUF,0,2); b3=RDB(BUF,0,3); \
    if (G1) STAGE_A(1-(BUF), 1, OFE1) \
    PHASE_CORE(0) \
    WAITV(6); \
    a0=RDA(BUF,0,1,0); a1=RDA(BUF,0,1,1); a2=RDA(BUF,0,1,2); a3=RDA(BUF,0,1,3); \
    if (G1) STAGE_B(1-(BUF), 1, OFE1) \
    PHASE_CORE(4) \
    a0=RDA(BUF,1,0,0); a1=RDA(BUF,1,0,1); a2=RDA(BUF,1,0,2); a3=RDA(BUF,1,0,3); \
    b0=RDB(BUF,1,0); b1=RDB(BUF,1,1); b2=RDB(BUF,1,2); b3=RDB(BUF,1,3); \
    if (G2) STAGE_A(BUF, 0, OFE2) \
    PHASE_CORE(0) \
    a0=RDA(BUF,1,1,0); a1=RDA(BUF,1,1,1); a2=RDA(BUF,1,1,2); a3=RDA(BUF,1,1,3); \
    if (G2) STAGE_B(BUF, 0, OFE2) \
    PHASE_CORE(4) \
    if (G2)        { WAITV(6); } \
    else if (NEXT) { WAITV(0); } \
    __builtin_amdgcn_s_barrier(); \
    __builtin_amdgcn_sched_barrier(0); \
  }

__global__ __launch_bounds__(512, 2) void gemm_kernel(const ushort* __restrict__ A,
                                                      const ushort* __restrict__ Bt,
                                                      float* __restrict__ C) {
    __shared__ __align__(16) ushort lA[2][2][256 * 32];
    __shared__ __align__(16) ushort lB[2][2][256 * 32];

    const int tid = threadIdx.x;
    const int lane = tid & 63;
    const int wave = tid >> 6;

    const int nbn = DOUT / 256;               // 16
    const int nwg = gridDim.x;                // 512 (multiple of 8)
    int bid = blockIdx.x;
    int cpx = nwg >> 3;
    int s = (bid & 7) * cpx + (bid >> 3);     // XCD-contiguous chunks
    const int m0 = (s / nbn) * 256;
    const int n0 = (s % nbn) * 256;

    const int wr = wave >> 2;                 // 0..1  (M half)
    const int wc = wave & 3;                  // 0..3  (N quarter)
    const int fr = lane & 15;
    const int fq = lane >> 4;                 // 0..3

    const int st_r = tid >> 2;                // 0..127

    // per-thread constant offsets (ushort elems); read swizzle elem-xor ((fr>>1)&3)<<3
    const int sx = ((fr >> 1) & 3) << 3;
    const int aoff = (wr * 128 + fr) * 32 + ((fq << 3) ^ sx);
    const int boff = (wc * 64 + fr) * 32 + ((fq << 3) ^ sx);
    const int doff = tid * 8;                 // linear stage dest
    const int sce = ((tid & 3) << 3) ^ (((st_r >> 1) & 3) << 3);   // inv-swz source
    const ushort* gA0 = A  + (size_t)(m0 + st_r) * DIN + sce;
    const ushort* gA1 = gA0 + (size_t)128 * DIN;
    const ushort* gB0 = Bt + (size_t)(n0 + st_r) * DIN + sce;
    const ushort* gB1 = gB0 + (size_t)128 * DIN;

    f32x4 acc[8][4] = {};

    // prologue: tile0 both halves + tile1.kk0 staged (12 GLL/wave)
    STAGE_A(0, 0, 0)   STAGE_B(0, 0, 0)
    STAGE_A(0, 1, 32)  STAGE_B(0, 1, 32)
    STAGE_A(1, 0, 64)  STAGE_B(1, 0, 64)
    WAITV(6);
    __builtin_amdgcn_s_barrier();
    __builtin_amdgcn_sched_barrier(0);

    for (int u = 0; u < NT; u += 2) {
        KTILE(0, 1, (u + 2 < NT), 1, 96, 128)
        KTILE(1, (u + 2 < NT), (u + 3 < NT), (u + 2 < NT), 160, 192)
        gA0 += 128; gA1 += 128; gB0 += 128; gB1 += 128;
    }

    // epilogue: C/D frag layout col=fr, row=fq*4+j
#pragma unroll
    for (int a = 0; a < 8; ++a) {
        int grow = m0 + wr * 128 + (a >> 2) * 64 + (a & 3) * 16 + fq * 4;
#pragma unroll
        for (int n = 0; n < 4; ++n) {
            int gcol = n0 + wc * 64 + n * 16 + fr;
#pragma unroll
            for (int j = 0; j < 4; ++j)
                C[(size_t)(grow + j) * DOUT + gcol] = acc[a][n][j];
        }
    }
}

extern "C" void kernel_launch(void* const* d_in, const int* in_sizes, int n_in,
                              void* d_out, int out_size, void* d_ws, size_t ws_size,
                              hipStream_t stream) {
    const float* x = (const float*)d_in[0];
    const float* base = (const float*)d_in[1];
    const float* coeff = (const float*)d_in[2];
    const int* mask = (const int*)d_in[3];
    float* out = (float*)d_out;

    const int M = in_sizes[0] / DIN;           // 8192
    ushort* xb = (ushort*)d_ws;                // M*DIN bf16  (64 MB)
    ushort* wt = xb + (size_t)M * DIN;         // DOUT*DIN bf16 (32 MB)

    long n8 = (long)M * DIN / 8;
    cvt_x_kernel<<<(int)((n8 + 255) / 256), 256, 0, stream>>>(x, xb, n8);
    make_wt_kernel<<<(DIN / 64) * (DOUT / 64), 256, 0, stream>>>(base, mask, coeff, wt);

    const int nwg = (M / 256) * (DOUT / 256);  // 512
    gemm_kernel<<<nwg, 512, 0, stream>>>(xb, wt, out);
}